// Round 1
// baseline (1182.559 us; speedup 1.0000x reference)
//
#include <hip/hip_runtime.h>

// Sparse graph attention, f32 baseline.
// Layout: channel c in [0,128): head h = c & 7, dim d = c >> 3  (reshape (n,D,H) row-major).
// ws layout (floats): qp[N*128] | kp[N*128] | vp[N*128] | segmax(u32)[N*8] | denom[N*8] | num[N*128]
//   = ~105.6 MB total.

#define HC 128
#define NH 8
#define ND 16

__device__ __forceinline__ unsigned enc_f32(float f) {
  unsigned u = __float_as_uint(f);
  return (u & 0x80000000u) ? ~u : (u | 0x80000000u);  // monotone float->uint; 0 < enc(-inf)
}
__device__ __forceinline__ float dec_f32(unsigned u) {
  return (u & 0x80000000u) ? __uint_as_float(u ^ 0x80000000u) : __uint_as_float(~u);
}
__device__ __forceinline__ void atom_add_f32(float* p, float v) {
  __hip_atomic_fetch_add(p, v, __ATOMIC_RELAXED, __HIP_MEMORY_SCOPE_AGENT);
}

// ---------------- Kernel A: node projections q = query@Wq, [k|v] = key@Wkv ----------------
__global__ __launch_bounds__(256) void proj_kernel(
    const float* __restrict__ query, const float* __restrict__ key,
    const float* __restrict__ Wq, const float* __restrict__ Wkv,
    float* __restrict__ qp, float* __restrict__ kp, float* __restrict__ vp, int N) {
  __shared__ float q_lds[16][HC];
  __shared__ float k_lds[16][HC];
  const int tid = threadIdx.x;
  const int base = blockIdx.x * 16;
  for (int i = tid; i < 16 * HC; i += 256) {
    int e = i >> 7, c = i & 127;
    int node = base + e;
    float qv = 0.f, kv = 0.f;
    if (node < N) {
      qv = query[(size_t)node * HC + c];
      kv = key[(size_t)node * HC + c];
    }
    q_lds[e][c] = qv;
    k_lds[e][c] = kv;
  }
  __syncthreads();
  // q projection: col j of Wq for 8 nodes per thread
  {
    int j = tid & 127, e0 = tid >> 7;
    float acc[8] = {0.f, 0.f, 0.f, 0.f, 0.f, 0.f, 0.f, 0.f};
    for (int c = 0; c < HC; ++c) {
      float w = Wq[c * 128 + j];
#pragma unroll
      for (int r = 0; r < 8; ++r) acc[r] += q_lds[e0 + 2 * r][c] * w;
    }
#pragma unroll
    for (int r = 0; r < 8; ++r) {
      int node = base + e0 + 2 * r;
      if (node < N) qp[(size_t)node * 128 + j] = acc[r];
    }
  }
  // kv projection: col tid of Wkv (0..127 -> k, 128..255 -> v) for all 16 nodes
  {
    float acc[16];
#pragma unroll
    for (int e = 0; e < 16; ++e) acc[e] = 0.f;
    for (int c = 0; c < HC; ++c) {
      float w = Wkv[c * 256 + tid];
#pragma unroll
      for (int e = 0; e < 16; ++e) acc[e] += k_lds[e][c] * w;
    }
    float* dst = (tid < 128) ? kp : vp;
    int j = tid & 127;
#pragma unroll
    for (int e = 0; e < 16; ++e) {
      int node = base + e;
      if (node < N) dst[(size_t)node * 128 + j] = acc[e];
    }
  }
}

// ---------------- Kernel B: per-edge bias GEMM + logits + atomic segment max ----------------
__global__ __launch_bounds__(256) void edge_logit_kernel(
    const float* __restrict__ pr, const float* __restrict__ Wb,
    const float* __restrict__ qp, const float* __restrict__ kp,
    const int* __restrict__ qidx, const int* __restrict__ kidx,
    float* __restrict__ out_logit, unsigned* __restrict__ segmax, int M) {
  __shared__ float pr_lds[16][HC];   // 8 KB
  __shared__ float b_lds[16][256];   // 16 KB
  const int tid = threadIdx.x;
  const int base = blockIdx.x * 16;
  for (int i = tid; i < 16 * HC; i += 256) {
    int e = i >> 7, c = i & 127;
    int m = base + e;
    pr_lds[e][c] = (m < M) ? pr[(size_t)m * HC + c] : 0.f;
  }
  __syncthreads();
  // b[e][tid] = sum_c pr[e][c] * Wb[c][tid]   (thread owns one of 256 bias columns)
  float acc[16];
#pragma unroll
  for (int e = 0; e < 16; ++e) acc[e] = 0.f;
  for (int c = 0; c < HC; c += 4) {
    float w0 = Wb[(c + 0) * 256 + tid];
    float w1 = Wb[(c + 1) * 256 + tid];
    float w2 = Wb[(c + 2) * 256 + tid];
    float w3 = Wb[(c + 3) * 256 + tid];
#pragma unroll
    for (int e = 0; e < 16; ++e) {
      float4 p = *(const float4*)&pr_lds[e][c];
      acc[e] += p.x * w0 + p.y * w1 + p.z * w2 + p.w * w3;
    }
  }
#pragma unroll
  for (int e = 0; e < 16; ++e) b_lds[e][tid] = acc[e];
  __syncthreads();
  // logits: 8 threads per edge, thread = (e, h). c = d*8 + h.
  if (tid < 128) {
    int e = tid >> 3, h = tid & 7;
    int m = base + e;
    if (m < M) {
      int qi = qidx[m], ki = kidx[m];
      const float* qrow = qp + (size_t)qi * 128;
      const float* krow = kp + (size_t)ki * 128;
      float s = 0.f;
#pragma unroll
      for (int d = 0; d < ND; ++d) {
        int c = d * 8 + h;
        float bm = b_lds[e][c];
        float ba = b_lds[e][c + 128];
        s += qrow[c] * (krow[c] * (1.f + bm) + ba);
      }
      out_logit[(size_t)m * 8 + h] = s;
      atomicMax(&segmax[(size_t)qi * 8 + h], enc_f32(s));
    }
  }
}

// ---------------- Kernel C: exp + atomic accumulation of denom and numerator ----------------
__global__ __launch_bounds__(256) void edge_accum_kernel(
    const float* __restrict__ vp, const int* __restrict__ qidx,
    const int* __restrict__ kidx, const float* __restrict__ logit,
    const unsigned* __restrict__ segmax, float* __restrict__ denom,
    float* __restrict__ num, int M) {
  long long g = (long long)blockIdx.x * 256 + threadIdx.x;
  if (g >= (long long)M * 128) return;
  int m = (int)(g >> 7);
  int c = (int)(g & 127);
  int h = c & 7;
  int qi = qidx[m], ki = kidx[m];
  float lg = logit[(size_t)m * 8 + h];
  float mx = dec_f32(segmax[(size_t)qi * 8 + h]);
  float ex = expf(lg - mx);
  float v = vp[(size_t)ki * 128 + c];
  atom_add_f32(&num[(size_t)qi * 128 + c], ex * v);
  if (c < 8) atom_add_f32(&denom[(size_t)qi * 8 + c], ex);
}

// ---------------- Kernel D: result = (num/denom) @ Wo ----------------
__global__ __launch_bounds__(256) void out_kernel(
    const float* __restrict__ num, const float* __restrict__ denom,
    const float* __restrict__ Wo, float* __restrict__ out, int N) {
  __shared__ float agg[16][HC];
  const int tid = threadIdx.x;
  const int base = blockIdx.x * 16;
  for (int i = tid; i < 16 * HC; i += 256) {
    int e = i >> 7, c = i & 127;
    int node = base + e;
    float val = 0.f;
    if (node < N) {
      float dn = denom[(size_t)node * 8 + (c & 7)];
      if (dn > 0.f) val = num[(size_t)node * 128 + c] / dn;  // empty segment -> 0
    }
    agg[e][c] = val;
  }
  __syncthreads();
  int j = tid & 127, e0 = tid >> 7;
  float acc[8] = {0.f, 0.f, 0.f, 0.f, 0.f, 0.f, 0.f, 0.f};
  for (int c = 0; c < HC; ++c) {
    float w = Wo[c * 128 + j];
#pragma unroll
    for (int r = 0; r < 8; ++r) acc[r] += agg[e0 + 2 * r][c] * w;
  }
#pragma unroll
  for (int r = 0; r < 8; ++r) {
    int node = base + e0 + 2 * r;
    if (node < N) out[(size_t)node * 128 + j] = acc[r];
  }
}

extern "C" void kernel_launch(void* const* d_in, const int* in_sizes, int n_in,
                              void* d_out, int out_size, void* d_ws, size_t ws_size,
                              hipStream_t stream) {
  const float* query = (const float*)d_in[0];
  const float* key   = (const float*)d_in[1];
  const int*   qidx  = (const int*)d_in[2];
  const int*   kidx  = (const int*)d_in[3];
  const float* pr    = (const float*)d_in[4];
  const float* Wq    = (const float*)d_in[5];
  const float* Wkv   = (const float*)d_in[6];
  const float* Wb    = (const float*)d_in[7];
  const float* Wo    = (const float*)d_in[8];

  const int N = in_sizes[0] / HC;   // 50000
  const int M = in_sizes[2];        // 400000

  float* out_result = (float*)d_out;                       // N*128
  float* out_logit  = (float*)d_out + (size_t)N * HC;      // M*8

  float*    qp     = (float*)d_ws;
  float*    kp     = qp + (size_t)N * HC;
  float*    vp     = kp + (size_t)N * HC;
  unsigned* segmax = (unsigned*)(vp + (size_t)N * HC);
  float*    denom  = (float*)(segmax + (size_t)N * NH);
  float*    num    = denom + (size_t)N * NH;

  // zero-init accumulators (ws is poisoned 0xAA before every launch)
  hipMemsetAsync(segmax, 0, (size_t)N * NH * sizeof(unsigned), stream);  // enc(-inf) < 1
  hipMemsetAsync(denom, 0, (size_t)N * NH * sizeof(float), stream);
  hipMemsetAsync(num, 0, (size_t)N * HC * sizeof(float), stream);

  proj_kernel<<<(N + 15) / 16, 256, 0, stream>>>(query, key, Wq, Wkv, qp, kp, vp, N);
  edge_logit_kernel<<<(M + 15) / 16, 256, 0, stream>>>(pr, Wb, qp, kp, qidx, kidx,
                                                       out_logit, segmax, M);
  long long tot = (long long)M * HC;
  edge_accum_kernel<<<(unsigned)((tot + 255) / 256), 256, 0, stream>>>(
      vp, qidx, kidx, out_logit, segmax, denom, num, M);
  out_kernel<<<(N + 15) / 16, 256, 0, stream>>>(num, denom, Wo, out_result, N);
}

// Round 2
// 925.090 us; speedup vs baseline: 1.2783x; 1.2783x over previous
//
#include <hip/hip_runtime.h>

// Sparse graph attention. Layout: channel c in [0,128): head h = c & 7, dim d = c >> 3.
// Pipeline:
//   memset(cnt) -> count -> scan (CSR offsets) -> convert Wb -> proj ->
//   edge_logit_mfma (bias GEMM in bf16 MFMA + logits) -> fill (CSR lists) ->
//   node_agg (softmax + weighted V, no float atomics) -> out GEMM.
// ws: qp[N*128] kp[N*128] vp[N*128] agg[N*128] f32 | WbTp[4][256][32] bf16 | cnt[N] off[N+1] el[M] i32

#define HC 128
#define NH 8
#define ND 16

typedef __attribute__((ext_vector_type(8))) short bf16x8;
typedef __attribute__((ext_vector_type(4))) float f32x4;
typedef __attribute__((ext_vector_type(4))) unsigned int u32x4;

static __device__ __forceinline__ unsigned short f2bf(float f) {  // RNE
  unsigned u = __float_as_uint(f);
  unsigned r = 0x7fffu + ((u >> 16) & 1u);
  return (unsigned short)((u + r) >> 16);
}
static __device__ __forceinline__ float bf2f(unsigned short h) {
  return __uint_as_float(((unsigned)h) << 16);
}

// ---------------- Wb (128x256 f32) -> WbTp[kt][j][kk] bf16, kt=k/32, j=bias col, kk=k%32
__global__ __launch_bounds__(256) void convert_wb_kernel(
    const float* __restrict__ Wb, unsigned short* __restrict__ WbTp) {
  int idx = blockIdx.x * 256 + threadIdx.x;   // 32768 total
  int kt = idx >> 13, j = (idx >> 5) & 255, kk = idx & 31;
  WbTp[idx] = f2bf(Wb[(kt * 32 + kk) * 256 + j]);
}

// ---------------- CSR build ----------------
__global__ __launch_bounds__(256) void count_kernel(const int* __restrict__ qidx,
                                                    int* __restrict__ cnt, int M) {
  int m = blockIdx.x * 256 + threadIdx.x;
  if (m < M) atomicAdd(&cnt[qidx[m]], 1);
}

__global__ __launch_bounds__(1024) void scan_kernel(int* __restrict__ cnt,
                                                    int* __restrict__ off, int N) {
  __shared__ int partial[1024];
  const int tid = threadIdx.x;
  const int K = (N + 1023) / 1024;
  const int lo = tid * K;
  int s = 0;
  for (int i = 0; i < K; ++i) {
    int idx = lo + i;
    if (idx < N) s += cnt[idx];
  }
  partial[tid] = s;
  __syncthreads();
  for (int d = 1; d < 1024; d <<= 1) {
    int t = (tid >= d) ? partial[tid - d] : 0;
    __syncthreads();
    partial[tid] += t;
    __syncthreads();
  }
  int run = partial[tid] - s;  // exclusive prefix of this thread's range
  for (int i = 0; i < K; ++i) {
    int idx = lo + i;
    if (idx < N) {
      off[idx] = run;
      run += cnt[idx];
      cnt[idx] = 0;  // becomes the fill cursor
    }
  }
  if (tid == 1023) off[N] = run;  // == M
}

__global__ __launch_bounds__(256) void fill_kernel(const int* __restrict__ qidx,
                                                   int* __restrict__ cursor,
                                                   const int* __restrict__ off,
                                                   int* __restrict__ el, int M) {
  int m = blockIdx.x * 256 + threadIdx.x;
  if (m < M) {
    int qi = qidx[m];
    int pos = atomicAdd(&cursor[qi], 1);
    el[off[qi] + pos] = m;
  }
}

// ---------------- node projections (f32 VALU; small) ----------------
__global__ __launch_bounds__(256) void proj_kernel(
    const float* __restrict__ query, const float* __restrict__ key,
    const float* __restrict__ Wq, const float* __restrict__ Wkv,
    float* __restrict__ qp, float* __restrict__ kp, float* __restrict__ vp, int N) {
  __shared__ float q_lds[16][HC];
  __shared__ float k_lds[16][HC];
  const int tid = threadIdx.x;
  const int base = blockIdx.x * 16;
  for (int i = tid; i < 16 * HC; i += 256) {
    int e = i >> 7, c = i & 127;
    int node = base + e;
    float qv = 0.f, kv = 0.f;
    if (node < N) {
      qv = query[(size_t)node * HC + c];
      kv = key[(size_t)node * HC + c];
    }
    q_lds[e][c] = qv;
    k_lds[e][c] = kv;
  }
  __syncthreads();
  {
    int j = tid & 127, e0 = tid >> 7;
    float acc[8] = {0.f, 0.f, 0.f, 0.f, 0.f, 0.f, 0.f, 0.f};
    for (int c = 0; c < HC; ++c) {
      float w = Wq[c * 128 + j];
#pragma unroll
      for (int r = 0; r < 8; ++r) acc[r] += q_lds[e0 + 2 * r][c] * w;
    }
#pragma unroll
    for (int r = 0; r < 8; ++r) {
      int node = base + e0 + 2 * r;
      if (node < N) qp[(size_t)node * 128 + j] = acc[r];
    }
  }
  {
    float acc[16];
#pragma unroll
    for (int e = 0; e < 16; ++e) acc[e] = 0.f;
    for (int c = 0; c < HC; ++c) {
      float w = Wkv[c * 256 + tid];
#pragma unroll
      for (int e = 0; e < 16; ++e) acc[e] += k_lds[e][c] * w;
    }
    float* dst = (tid < 128) ? kp : vp;
    int j = tid & 127;
#pragma unroll
    for (int e = 0; e < 16; ++e) {
      int node = base + e;
      if (node < N) dst[(size_t)node * 128 + j] = acc[e];
    }
  }
}

// ---------------- edge logits: bias GEMM via bf16 MFMA + dot ----------------
// 64 edges/block, 4 waves. LDS: pr_bf16[64][128] (swizzled, 16KB) then b_bf16[64][264-pad] (~33KB).
#define BLS 264  // padded bf16 row stride for the bias tile
__global__ __launch_bounds__(256) void edge_logit_mfma(
    const float* __restrict__ pr, const unsigned short* __restrict__ WbTp,
    const float* __restrict__ qp, const float* __restrict__ kp,
    const int* __restrict__ qidx, const int* __restrict__ kidx,
    float* __restrict__ out_logit, int M) {
  __shared__ unsigned char lds[64 * BLS * 2];  // 33792 B
  const int tid = threadIdx.x;
  const int base = blockIdx.x * 64;

  // stage pr tile -> bf16 LDS with XOR swizzle (16B chunk granularity)
#pragma unroll
  for (int i = 0; i < 4; ++i) {
    int q = tid + 256 * i;  // 1024 chunks: 64 rows x 16 chunks of 8 elems
    int row = q >> 4, cr = q & 15;
    int m = base + row;
    float4 p0 = {0.f, 0.f, 0.f, 0.f}, p1 = p0;
    if (m < M) {
      const float4* src = (const float4*)(pr + (size_t)m * HC + cr * 8);
      p0 = src[0];
      p1 = src[1];
    }
    unsigned v0 = (unsigned)f2bf(p0.x) | ((unsigned)f2bf(p0.y) << 16);
    unsigned v1 = (unsigned)f2bf(p0.z) | ((unsigned)f2bf(p0.w) << 16);
    unsigned v2 = (unsigned)f2bf(p1.x) | ((unsigned)f2bf(p1.y) << 16);
    unsigned v3 = (unsigned)f2bf(p1.z) | ((unsigned)f2bf(p1.w) << 16);
    u32x4 pk = {v0, v1, v2, v3};
    int byte = row * 256 + ((cr * 16) ^ ((row & 7) << 4));
    *(u32x4*)(lds + byte) = pk;
  }
  __syncthreads();

  // A-fragments: row = lane&15 within wave's 16-row slab; 8 contiguous k per lane
  const int lane = tid & 63, w = tid >> 6;
  const int arow = w * 16 + (lane & 15);
  bf16x8 a[4];
#pragma unroll
  for (int kt = 0; kt < 4; ++kt) {
    int byte = arow * 256 + ((kt * 64 + ((lane >> 4) * 16)) ^ ((arow & 7) << 4));
    a[kt] = *(const bf16x8*)(lds + byte);
  }
  __syncthreads();  // pr region about to be overwritten by bias tile

  // b[64][256] = pr @ Wb : each wave 16 rows x 16 col-tiles, K=128 (4 MFMA each)
  f32x4 acc[16];
#pragma unroll
  for (int n = 0; n < 16; ++n) acc[n] = (f32x4){0.f, 0.f, 0.f, 0.f};
#pragma unroll
  for (int kt = 0; kt < 4; ++kt) {
#pragma unroll
    for (int n = 0; n < 16; ++n) {
      bf16x8 b = *(const bf16x8*)(WbTp + kt * 8192 + (n * 16 + (lane & 15)) * 32 +
                                  (lane >> 4) * 8);
      acc[n] = __builtin_amdgcn_mfma_f32_16x16x32_bf16(a[kt], b, acc[n], 0, 0, 0);
    }
  }

  // write bias tile to LDS as bf16 with padded stride (kills epilogue bank conflicts)
  unsigned short* bl = (unsigned short*)lds;
  {
    int col = (lane & 15);
    int r0 = w * 16 + (lane >> 4) * 4;
#pragma unroll
    for (int n = 0; n < 16; ++n) {
#pragma unroll
      for (int r = 0; r < 4; ++r) bl[(r0 + r) * BLS + n * 16 + col] = f2bf(acc[n][r]);
    }
  }
  __syncthreads();

  // logit epilogue: unit = (edge, head)
#pragma unroll
  for (int rep = 0; rep < 2; ++rep) {
    int unit = rep * 256 + tid;
    int e = unit >> 3, h = unit & 7;
    int m = base + e;
    if (m < M) {
      int qi = qidx[m], ki = kidx[m];
      const float* qrow = qp + (size_t)qi * HC;
      const float* krow = kp + (size_t)ki * HC;
      float s = 0.f;
#pragma unroll
      for (int d = 0; d < ND; ++d) {
        int c = d * 8 + h;
        float bm = bf2f(bl[e * BLS + c]);
        float ba = bf2f(bl[e * BLS + c + 128]);
        s += qrow[c] * (krow[c] * (1.f + bm) + ba);
      }
      out_logit[(size_t)m * 8 + h] = s;
    }
  }
}

// ---------------- per-node softmax + weighted V (no float atomics) ----------------
__global__ __launch_bounds__(128) void node_agg_kernel(
    const float* __restrict__ vp, const float* __restrict__ logit,
    const int* __restrict__ kidx, const int* __restrict__ off,
    const int* __restrict__ el, float* __restrict__ agg, int N) {
  const int n = blockIdx.x;
  const int c = threadIdx.x;  // 0..127
  const int h = c & 7;
  const int s = off[n], e = off[n + 1];
  float mx = -1e30f;
  for (int i = s; i < e; ++i) {
    int m = el[i];
    mx = fmaxf(mx, logit[(size_t)m * 8 + h]);
  }
  float acc = 0.f, dsum = 0.f;
  for (int i = s; i < e; ++i) {
    int m = el[i];
    float ex = __expf(logit[(size_t)m * 8 + h] - mx);
    acc += ex * vp[(size_t)kidx[m] * HC + c];
    dsum += ex;
  }
  agg[(size_t)n * HC + c] = (e > s) ? acc / dsum : 0.f;
}

// ---------------- result = agg @ Wo ----------------
__global__ __launch_bounds__(256) void out_kernel(
    const float* __restrict__ agg, const float* __restrict__ Wo,
    float* __restrict__ out, int N) {
  __shared__ float a_lds[16][HC];
  const int tid = threadIdx.x;
  const int base = blockIdx.x * 16;
  for (int i = tid; i < 16 * HC; i += 256) {
    int e = i >> 7, c = i & 127;
    int node = base + e;
    a_lds[e][c] = (node < N) ? agg[(size_t)node * 128 + c] : 0.f;
  }
  __syncthreads();
  int j = tid & 127, e0 = tid >> 7;
  float acc[8] = {0.f, 0.f, 0.f, 0.f, 0.f, 0.f, 0.f, 0.f};
  for (int c = 0; c < HC; ++c) {
    float w = Wo[c * 128 + j];
#pragma unroll
    for (int r = 0; r < 8; ++r) acc[r] += a_lds[e0 + 2 * r][c] * w;
  }
#pragma unroll
  for (int r = 0; r < 8; ++r) {
    int node = base + e0 + 2 * r;
    if (node < N) out[(size_t)node * 128 + j] = acc[r];
  }
}

extern "C" void kernel_launch(void* const* d_in, const int* in_sizes, int n_in,
                              void* d_out, int out_size, void* d_ws, size_t ws_size,
                              hipStream_t stream) {
  const float* query = (const float*)d_in[0];
  const float* key   = (const float*)d_in[1];
  const int*   qidx  = (const int*)d_in[2];
  const int*   kidx  = (const int*)d_in[3];
  const float* pr    = (const float*)d_in[4];
  const float* Wq    = (const float*)d_in[5];
  const float* Wkv   = (const float*)d_in[6];
  const float* Wb    = (const float*)d_in[7];
  const float* Wo    = (const float*)d_in[8];

  const int N = in_sizes[0] / HC;  // 50000
  const int M = in_sizes[2];       // 400000

  float* out_result = (float*)d_out;
  float* out_logit  = (float*)d_out + (size_t)N * HC;

  float* qp  = (float*)d_ws;
  float* kp  = qp + (size_t)N * HC;
  float* vp  = kp + (size_t)N * HC;
  float* agg = vp + (size_t)N * HC;
  unsigned short* WbTp = (unsigned short*)(agg + (size_t)N * HC);
  int* cnt = (int*)(WbTp + 4 * 256 * 32);
  int* off = cnt + N;
  int* el  = off + (N + 1);

  hipMemsetAsync(cnt, 0, (size_t)N * sizeof(int), stream);
  count_kernel<<<(M + 255) / 256, 256, 0, stream>>>(qidx, cnt, M);
  scan_kernel<<<1, 1024, 0, stream>>>(cnt, off, N);
  convert_wb_kernel<<<128, 256, 0, stream>>>(Wb, WbTp);
  proj_kernel<<<(N + 15) / 16, 256, 0, stream>>>(query, key, Wq, Wkv, qp, kp, vp, N);
  edge_logit_mfma<<<(M + 63) / 64, 256, 0, stream>>>(pr, WbTp, qp, kp, qidx, kidx,
                                                     out_logit, M);
  fill_kernel<<<(M + 255) / 256, 256, 0, stream>>>(qidx, cnt, off, el, M);
  node_agg_kernel<<<N, 128, 0, stream>>>(vp, out_logit, kidx, off, el, agg, N);
  out_kernel<<<(N + 15) / 16, 256, 0, stream>>>(agg, Wo, out_result, N);
}

// Round 3
// 788.821 us; speedup vs baseline: 1.4991x; 1.1728x over previous
//
#include <hip/hip_runtime.h>

// Sparse graph attention, MFMA-everywhere version.
// channel c in [0,128): head h = c&7, dim d = c>>3.
// Pipeline: memset(cnt) -> count -> scan -> fill(el2=(m,ki)) -> convert W (bf16 pack) ->
//   proj_mfma (q,k,v bf16) -> edge_logit_mfma (bias GEMM + wave-per-edge logits) ->
//   node_agg (wave-per-node online softmax) -> out_mfma.
// MFMA mapping (verified R2 on real data): A: row=lane&15, k=(lane>>4)*8+j ; B: col=lane&15,
// k=(lane>>4)*8+j ; C: col=lane&15, row=(lane>>4)*4+r.

#define HC 128
#define NH 8

typedef __attribute__((ext_vector_type(8))) short bf16x8;
typedef __attribute__((ext_vector_type(4))) float f32x4;
typedef __attribute__((ext_vector_type(4))) unsigned int u32x4;

static __device__ __forceinline__ unsigned short f2bf(float f) {  // RNE
  unsigned u = __float_as_uint(f);
  unsigned r = 0x7fffu + ((u >> 16) & 1u);
  return (unsigned short)((u + r) >> 16);
}
static __device__ __forceinline__ float bf2f(unsigned short h) {
  return __uint_as_float(((unsigned)h) << 16);
}
static __device__ __forceinline__ float bflo(unsigned w) { return __uint_as_float(w << 16); }
static __device__ __forceinline__ float bfhi(unsigned w) { return __uint_as_float(w & 0xffff0000u); }

// ---------------- pack Wq,Wkv,Wb,Wo -> bf16 [kt][j][kk] (kt=k/32, kk=k%32) ----------------
__global__ __launch_bounds__(256) void convert_w_kernel(
    const float* __restrict__ Wq, const float* __restrict__ Wkv,
    const float* __restrict__ Wb, const float* __restrict__ Wo,
    unsigned short* __restrict__ P) {
  int idx = blockIdx.x * 256 + threadIdx.x;  // 98304 total
  const float* W;
  int cols, local;
  if (idx < 16384) { W = Wq; cols = 128; local = idx; }
  else if (idx < 49152) { W = Wkv; cols = 256; local = idx - 16384; }
  else if (idx < 81920) { W = Wb; cols = 256; local = idx - 49152; }
  else { W = Wo; cols = 128; local = idx - 81920; }
  int kt = local / (cols * 32);
  int j = (local / 32) % cols;
  int kk = local & 31;
  P[idx] = f2bf(W[(kt * 32 + kk) * cols + j]);
}

// ---------------- CSR build ----------------
__global__ __launch_bounds__(256) void count_kernel(const int* __restrict__ qidx,
                                                    int* __restrict__ cnt, int M) {
  int m = blockIdx.x * 256 + threadIdx.x;
  if (m < M) atomicAdd(&cnt[qidx[m]], 1);
}

__global__ __launch_bounds__(1024) void scan_kernel(int* __restrict__ cnt,
                                                    int* __restrict__ off, int N) {
  __shared__ int partial[1024];
  const int tid = threadIdx.x;
  const int K = (N + 1023) / 1024;
  const int lo = tid * K;
  int s = 0;
  for (int i = 0; i < K; ++i) {
    int idx = lo + i;
    if (idx < N) s += cnt[idx];
  }
  partial[tid] = s;
  __syncthreads();
  for (int d = 1; d < 1024; d <<= 1) {
    int t = (tid >= d) ? partial[tid - d] : 0;
    __syncthreads();
    partial[tid] += t;
    __syncthreads();
  }
  int run = partial[tid] - s;
  for (int i = 0; i < K; ++i) {
    int idx = lo + i;
    if (idx < N) {
      off[idx] = run;
      run += cnt[idx];
      cnt[idx] = 0;  // fill cursor
    }
  }
  if (tid == 1023) off[N] = run;
}

__global__ __launch_bounds__(256) void fill_kernel(const int* __restrict__ qidx,
                                                   const int* __restrict__ kidx,
                                                   int* __restrict__ cursor,
                                                   const int* __restrict__ off,
                                                   int2* __restrict__ el2, int M) {
  int m = blockIdx.x * 256 + threadIdx.x;
  if (m < M) {
    int qi = qidx[m];
    int pos = atomicAdd(&cursor[qi], 1);
    int2 v; v.x = m; v.y = kidx[m];
    el2[off[qi] + pos] = v;
  }
}

// ---------------- proj: qp = query@Wq, [kp|vp] = key@Wkv (all bf16 out) ----------------
__global__ __launch_bounds__(256) void proj_mfma(
    const float* __restrict__ query, const float* __restrict__ key,
    const unsigned short* __restrict__ WqP, const unsigned short* __restrict__ WkvP,
    unsigned short* __restrict__ qpb, unsigned short* __restrict__ kpb,
    unsigned short* __restrict__ vpb, int N) {
  __shared__ unsigned char lds[32768];  // q tile 16K @0, k tile 16K @16384
  const int tid = threadIdx.x;
  const int base = blockIdx.x * 64;
  const int lane = tid & 63, w = tid >> 6;

  // stage query & key tiles -> bf16 LDS, swizzled 16B chunks
#pragma unroll
  for (int i = 0; i < 4; ++i) {
    int q = tid + 256 * i;       // 1024 chunks: 64 rows x 16 chunks
    int row = q >> 4, cr = q & 15;
    int node = base + row;
    float4 a0 = {0.f,0.f,0.f,0.f}, a1 = a0, b0 = a0, b1 = a0;
    if (node < N) {
      const float4* sq = (const float4*)(query + (size_t)node * HC + cr * 8);
      const float4* sk = (const float4*)(key + (size_t)node * HC + cr * 8);
      a0 = sq[0]; a1 = sq[1]; b0 = sk[0]; b1 = sk[1];
    }
    int byte = row * 256 + ((cr << 4) ^ ((row & 7) << 4));
    u32x4 pa = {(unsigned)f2bf(a0.x) | ((unsigned)f2bf(a0.y) << 16),
                (unsigned)f2bf(a0.z) | ((unsigned)f2bf(a0.w) << 16),
                (unsigned)f2bf(a1.x) | ((unsigned)f2bf(a1.y) << 16),
                (unsigned)f2bf(a1.z) | ((unsigned)f2bf(a1.w) << 16)};
    u32x4 pb = {(unsigned)f2bf(b0.x) | ((unsigned)f2bf(b0.y) << 16),
                (unsigned)f2bf(b0.z) | ((unsigned)f2bf(b0.w) << 16),
                (unsigned)f2bf(b1.x) | ((unsigned)f2bf(b1.y) << 16),
                (unsigned)f2bf(b1.z) | ((unsigned)f2bf(b1.w) << 16)};
    *(u32x4*)(lds + byte) = pa;
    *(u32x4*)(lds + 16384 + byte) = pb;
  }
  __syncthreads();

  const int arow = w * 16 + (lane & 15);
  bf16x8 aq[4], ak[4];
#pragma unroll
  for (int kt = 0; kt < 4; ++kt) {
    int byte = arow * 256 + ((kt * 64 + ((lane >> 4) * 16)) ^ ((arow & 7) << 4));
    aq[kt] = *(const bf16x8*)(lds + byte);
    ak[kt] = *(const bf16x8*)(lds + 16384 + byte);
  }
  __syncthreads();  // LDS about to be reused as output staging

  unsigned short* stg = (unsigned short*)lds;  // per-wave disjoint rows -> no barriers

  // ---- Q phase: 8 col-tiles ----
  {
    f32x4 acc[8];
#pragma unroll
    for (int n = 0; n < 8; ++n) acc[n] = (f32x4){0.f,0.f,0.f,0.f};
#pragma unroll
    for (int kt = 0; kt < 4; ++kt)
#pragma unroll
      for (int n = 0; n < 8; ++n) {
        bf16x8 b = *(const bf16x8*)(WqP + kt * 4096 + (n * 16 + (lane & 15)) * 32 + (lane >> 4) * 8);
        acc[n] = __builtin_amdgcn_mfma_f32_16x16x32_bf16(aq[kt], b, acc[n], 0, 0, 0);
      }
    int lc = lane & 15, r0 = w * 16 + (lane >> 4) * 4;
#pragma unroll
    for (int n = 0; n < 8; ++n)
#pragma unroll
      for (int r = 0; r < 4; ++r) {
        int row = r0 + r, col = n * 16 + lc;
        int byte = row * 256 + ((((col >> 3) ^ (row & 7)) << 4)) + (col & 7) * 2;
        *(unsigned short*)((unsigned char*)stg + byte) = f2bf(acc[n][r]);
      }
#pragma unroll
    for (int it = 0; it < 4; ++it) {
      int q = it * 64 + lane;
      int row = w * 16 + (q >> 4), ch = q & 15;
      int node = base + row;
      u32x4 v = *(const u32x4*)(lds + row * 256 + ((ch ^ (row & 7)) << 4));
      if (node < N) *(u32x4*)(qpb + (size_t)node * HC + ch * 8) = v;
    }
  }

  // ---- KV phase: 16 col-tiles (0..7 -> kp, 8..15 -> vp) ----
  {
    f32x4 acc[16];
#pragma unroll
    for (int n = 0; n < 16; ++n) acc[n] = (f32x4){0.f,0.f,0.f,0.f};
#pragma unroll
    for (int kt = 0; kt < 4; ++kt)
#pragma unroll
      for (int n = 0; n < 16; ++n) {
        bf16x8 b = *(const bf16x8*)(WkvP + kt * 8192 + (n * 16 + (lane & 15)) * 32 + (lane >> 4) * 8);
        acc[n] = __builtin_amdgcn_mfma_f32_16x16x32_bf16(ak[kt], b, acc[n], 0, 0, 0);
      }
    int lc = lane & 15, r0 = w * 16 + (lane >> 4) * 4;
#pragma unroll
    for (int half = 0; half < 2; ++half) {
#pragma unroll
      for (int n = 0; n < 8; ++n)
#pragma unroll
        for (int r = 0; r < 4; ++r) {
          int row = r0 + r, col = n * 16 + lc;
          int byte = row * 256 + ((((col >> 3) ^ (row & 7)) << 4)) + (col & 7) * 2;
          *(unsigned short*)((unsigned char*)stg + byte) = f2bf(acc[half * 8 + n][r]);
        }
      unsigned short* dst = half ? vpb : kpb;
#pragma unroll
      for (int it = 0; it < 4; ++it) {
        int q = it * 64 + lane;
        int row = w * 16 + (q >> 4), ch = q & 15;
        int node = base + row;
        u32x4 v = *(const u32x4*)(lds + row * 256 + ((ch ^ (row & 7)) << 4));
        if (node < N) *(u32x4*)(dst + (size_t)node * HC + ch * 8) = v;
      }
    }
  }
}

// ---------------- edge logits: bias GEMM (MFMA) + wave-per-edge epilogue ----------------
#define BLS 264  // padded bf16 row stride for bias tile
__global__ __launch_bounds__(256) void edge_logit_mfma(
    const float* __restrict__ pr, const unsigned short* __restrict__ WbP,
    const unsigned short* __restrict__ qpb, const unsigned short* __restrict__ kpb,
    const int* __restrict__ qidx, const int* __restrict__ kidx,
    float* __restrict__ out_logit, int M) {
  __shared__ unsigned char lds[64 * BLS * 2];  // 33792 B
  const int tid = threadIdx.x;
  const int base = blockIdx.x * 64;
  const int lane = tid & 63, w = tid >> 6;

  // stage pr tile -> bf16, swizzled
#pragma unroll
  for (int i = 0; i < 4; ++i) {
    int q = tid + 256 * i;
    int row = q >> 4, cr = q & 15;
    int m = base + row;
    float4 p0 = {0.f,0.f,0.f,0.f}, p1 = p0;
    if (m < M) {
      const float4* src = (const float4*)(pr + (size_t)m * HC + cr * 8);
      p0 = src[0]; p1 = src[1];
    }
    u32x4 pk = {(unsigned)f2bf(p0.x) | ((unsigned)f2bf(p0.y) << 16),
                (unsigned)f2bf(p0.z) | ((unsigned)f2bf(p0.w) << 16),
                (unsigned)f2bf(p1.x) | ((unsigned)f2bf(p1.y) << 16),
                (unsigned)f2bf(p1.z) | ((unsigned)f2bf(p1.w) << 16)};
    *(u32x4*)(lds + row * 256 + ((cr << 4) ^ ((row & 7) << 4))) = pk;
  }
  __syncthreads();

  const int arow = w * 16 + (lane & 15);
  bf16x8 a[4];
#pragma unroll
  for (int kt = 0; kt < 4; ++kt) {
    int byte = arow * 256 + ((kt * 64 + ((lane >> 4) * 16)) ^ ((arow & 7) << 4));
    a[kt] = *(const bf16x8*)(lds + byte);
  }
  __syncthreads();

  f32x4 acc[16];
#pragma unroll
  for (int n = 0; n < 16; ++n) acc[n] = (f32x4){0.f,0.f,0.f,0.f};
#pragma unroll
  for (int kt = 0; kt < 4; ++kt)
#pragma unroll
    for (int n = 0; n < 16; ++n) {
      bf16x8 b = *(const bf16x8*)(WbP + kt * 8192 + (n * 16 + (lane & 15)) * 32 + (lane >> 4) * 8);
      acc[n] = __builtin_amdgcn_mfma_f32_16x16x32_bf16(a[kt], b, acc[n], 0, 0, 0);
    }

  unsigned short* bl = (unsigned short*)lds;
  {
    int col = lane & 15, r0 = w * 16 + (lane >> 4) * 4;
#pragma unroll
    for (int n = 0; n < 16; ++n)
#pragma unroll
      for (int r = 0; r < 4; ++r) bl[(r0 + r) * BLS + n * 16 + col] = f2bf(acc[n][r]);
  }
  __syncthreads();

  // wave-per-edge epilogue: wave w owns edges w*16..w*16+15
#pragma unroll 2
  for (int i = 0; i < 16; ++i) {
    int e = w * 16 + i;
    int m = base + e;
    if (m < M) {
      int qi = qidx[m], ki = kidx[m];
      unsigned qw = *(const unsigned*)(qpb + (size_t)qi * HC + 2 * lane);
      unsigned kw = *(const unsigned*)(kpb + (size_t)ki * HC + 2 * lane);
      unsigned bmw = *(const unsigned*)(bl + e * BLS + 2 * lane);
      unsigned baw = *(const unsigned*)(bl + e * BLS + 128 + 2 * lane);
      float p0 = bflo(qw) * (bflo(kw) * (1.f + bflo(bmw)) + bflo(baw));
      float p1 = bfhi(qw) * (bfhi(kw) * (1.f + bfhi(bmw)) + bfhi(baw));
#pragma unroll
      for (int msk = 4; msk <= 32; msk <<= 1) {
        p0 += __shfl_xor(p0, msk);
        p1 += __shfl_xor(p1, msk);
      }
      if (lane < 4) {
        float2 v; v.x = p0; v.y = p1;
        *(float2*)(out_logit + (size_t)m * NH + 2 * lane) = v;
      }
    }
  }
}

// ---------------- wave-per-node online softmax + weighted V ----------------
__global__ __launch_bounds__(256) void node_agg_kernel(
    const unsigned short* __restrict__ vpb, const float* __restrict__ logit,
    const int* __restrict__ off, const int2* __restrict__ el2,
    unsigned short* __restrict__ aggb, int N) {
  const int lane = threadIdx.x & 63, w = threadIdx.x >> 6;
  const int n = blockIdx.x * 4 + w;
  if (n >= N) return;
  const int s = off[n], e = off[n + 1];
  const int t = lane & 3;
  float mx0 = -1e30f, mx1 = -1e30f, d0 = 0.f, d1 = 0.f, a0 = 0.f, a1 = 0.f;
  for (int i = s; i < e; ++i) {
    int2 me = el2[i];
    float2 lg = *(const float2*)(logit + (size_t)me.x * NH + 2 * t);
    unsigned vw = *(const unsigned*)(vpb + (size_t)me.y * HC + 2 * lane);
    float nm0 = fmaxf(mx0, lg.x), nm1 = fmaxf(mx1, lg.y);
    float s0 = __expf(mx0 - nm0), s1 = __expf(mx1 - nm1);
    float e0 = __expf(lg.x - nm0), e1 = __expf(lg.y - nm1);
    a0 = a0 * s0 + e0 * bflo(vw);
    a1 = a1 * s1 + e1 * bfhi(vw);
    d0 = d0 * s0 + e0;
    d1 = d1 * s1 + e1;
    mx0 = nm0; mx1 = nm1;
  }
  float r0 = (e > s) ? a0 / d0 : 0.f;
  float r1 = (e > s) ? a1 / d1 : 0.f;
  unsigned pk = (unsigned)f2bf(r0) | ((unsigned)f2bf(r1) << 16);
  *(unsigned*)(aggb + (size_t)n * HC + 2 * lane) = pk;
}

// ---------------- out = agg @ Wo (f32 out) ----------------
__global__ __launch_bounds__(256) void out_mfma(
    const unsigned short* __restrict__ aggb, const unsigned short* __restrict__ WoP,
    float* __restrict__ out, int N) {
  __shared__ unsigned char lds[16384 + 32768];  // bf16 in-tile + f32 out-stage
  const int tid = threadIdx.x;
  const int base = blockIdx.x * 64;
  const int lane = tid & 63, w = tid >> 6;

#pragma unroll
  for (int i = 0; i < 4; ++i) {
    int q = tid + 256 * i;
    int row = q >> 4, cr = q & 15;
    int node = base + row;
    u32x4 v = {0u,0u,0u,0u};
    if (node < N) v = *(const u32x4*)(aggb + (size_t)node * HC + cr * 8);
    *(u32x4*)(lds + row * 256 + ((cr << 4) ^ ((row & 7) << 4))) = v;
  }
  __syncthreads();

  const int arow = w * 16 + (lane & 15);
  bf16x8 a[4];
#pragma unroll
  for (int kt = 0; kt < 4; ++kt) {
    int byte = arow * 256 + ((kt * 64 + ((lane >> 4) * 16)) ^ ((arow & 7) << 4));
    a[kt] = *(const bf16x8*)(lds + byte);
  }

  f32x4 acc[8];
#pragma unroll
  for (int n = 0; n < 8; ++n) acc[n] = (f32x4){0.f,0.f,0.f,0.f};
#pragma unroll
  for (int kt = 0; kt < 4; ++kt)
#pragma unroll
    for (int n = 0; n < 8; ++n) {
      bf16x8 b = *(const bf16x8*)(WoP + kt * 4096 + (n * 16 + (lane & 15)) * 32 + (lane >> 4) * 8);
      acc[n] = __builtin_amdgcn_mfma_f32_16x16x32_bf16(a[kt], b, acc[n], 0, 0, 0);
    }

  float* fs = (float*)(lds + 16384);
  {
    int lc = lane & 15, r0 = w * 16 + (lane >> 4) * 4;
#pragma unroll
    for (int n = 0; n < 8; ++n)
#pragma unroll
      for (int r = 0; r < 4; ++r) {
        int row = r0 + r, col = n * 16 + lc;
        int byte = row * 512 + ((((col >> 2) ^ (row & 7)) << 4)) + (col & 3) * 4;
        *(float*)((unsigned char*)fs + byte) = acc[n][r];
      }
  }
#pragma unroll
  for (int it = 0; it < 8; ++it) {
    int q = it * 64 + lane;
    int row = w * 16 + (q >> 5), ch = q & 31;
    int node = base + row;
    f32x4 v = *(const f32x4*)((unsigned char*)fs + row * 512 + ((ch ^ (row & 7)) << 4));
    if (node < N) *(f32x4*)(out + (size_t)node * HC + ch * 4) = v;
  }
}

extern "C" void kernel_launch(void* const* d_in, const int* in_sizes, int n_in,
                              void* d_out, int out_size, void* d_ws, size_t ws_size,
                              hipStream_t stream) {
  const float* query = (const float*)d_in[0];
  const float* key   = (const float*)d_in[1];
  const int*   qidx  = (const int*)d_in[2];
  const int*   kidx  = (const int*)d_in[3];
  const float* pr    = (const float*)d_in[4];
  const float* Wq    = (const float*)d_in[5];
  const float* Wkv   = (const float*)d_in[6];
  const float* Wb    = (const float*)d_in[7];
  const float* Wo    = (const float*)d_in[8];

  const int N = in_sizes[0] / HC;  // 50000
  const int M = in_sizes[2];       // 400000

  float* out_result = (float*)d_out;
  float* out_logit  = (float*)d_out + (size_t)N * HC;

  unsigned short* qpb  = (unsigned short*)d_ws;
  unsigned short* kpb  = qpb + (size_t)N * HC;
  unsigned short* vpb  = kpb + (size_t)N * HC;
  unsigned short* aggb = vpb + (size_t)N * HC;
  unsigned short* WP   = aggb + (size_t)N * HC;
  unsigned short* WqP  = WP;
  unsigned short* WkvP = WP + 16384;
  unsigned short* WbP  = WP + 49152;
  unsigned short* WoP  = WP + 81920;
  int*  cnt = (int*)(WP + 98304);
  int*  off = cnt + N;
  int2* el2 = (int2*)(off + ((N + 4) & ~3));  // 8B aligned

  hipMemsetAsync(cnt, 0, (size_t)N * sizeof(int), stream);
  count_kernel<<<(M + 255) / 256, 256, 0, stream>>>(qidx, cnt, M);
  scan_kernel<<<1, 1024, 0, stream>>>(cnt, off, N);
  fill_kernel<<<(M + 255) / 256, 256, 0, stream>>>(qidx, kidx, cnt, off, el2, M);
  convert_w_kernel<<<384, 256, 0, stream>>>(Wq, Wkv, Wb, Wo, WP);
  proj_mfma<<<(N + 63) / 64, 256, 0, stream>>>(query, key, WqP, WkvP, qpb, kpb, vpb, N);
  edge_logit_mfma<<<(M + 63) / 64, 256, 0, stream>>>(pr, WbP, qpb, kpb, qidx, kidx,
                                                     out_logit, M);
  node_agg_kernel<<<(N + 3) / 4, 256, 0, stream>>>(vpb, out_logit, off, el2, aggb, N);
  out_mfma<<<(N + 63) / 64, 256, 0, stream>>>(aggb, WoP, out_result, N);
}